// Round 7
// baseline (135.846 us; speedup 1.0000x reference)
//
#include <hip/hip_runtime.h>
#include <math.h>

// ---------------------------------------------------------------------------
// MultiAttention, 3 launches:
//  1) conv: x->bf16, W->bf16^T, Vsum=0
//  2) gemm_qkv: 256x128-tile bf16 MFMA GEMM (BK=64, global_load_lds,
//     XOR-swizzled source), fused V column sums (atomics)
//  3) attn_fcln: per (b, 32-row chunk): LDS-staged band attention (closed
//     form: uniform -1e-9 tail + 3-term band) -> ctx in LDS (FC swizzle
//     layout) -> BK=32 double-buffered FC GEMM -> residual + LayerNorm.
// ---------------------------------------------------------------------------

typedef short     s8v  __attribute__((ext_vector_type(8)));   // 8 bf16
typedef float     f4v  __attribute__((ext_vector_type(4)));
typedef unsigned short us4v __attribute__((ext_vector_type(4)));
typedef unsigned short us8v __attribute__((ext_vector_type(8)));

__device__ __forceinline__ unsigned short f2b(float f) {
  union { float f; unsigned int u; } v; v.f = f;
  unsigned int u = v.u;
  return (unsigned short)((u + 0x7fffu + ((u >> 16) & 1u)) >> 16);  // RNE
}
__device__ __forceinline__ float b2f(unsigned short u) {
  union { unsigned int i; float f; } v; v.i = ((unsigned int)u) << 16;
  return v.f;
}
__device__ __forceinline__ void gload_lds16(const void* g, void* l) {
  __builtin_amdgcn_global_load_lds(
      (const __attribute__((address_space(1))) void*)g,
      (__attribute__((address_space(3))) void*)l, 16, 0, 0);
}

// ---------------- conv: x->bf16, W->bf16 transposed, Vsum=0 ----------------
__global__ __launch_bounds__(256) void conv_kernel(
    const float* __restrict__ x,
    const float* __restrict__ Wq, const float* __restrict__ Wk,
    const float* __restrict__ Wv, const float* __restrict__ Wfc,
    unsigned short* __restrict__ xb, unsigned short* __restrict__ Wt,
    float* __restrict__ Vsum) {
  __shared__ unsigned short tile[32][33];
  const int bid = blockIdx.x, t = threadIdx.x;
  if (bid < 4096) {
    const int i = bid * 256 + t;
    const float4 f = ((const float4*)x)[i];
    us4v o; o[0] = f2b(f.x); o[1] = f2b(f.y); o[2] = f2b(f.z); o[3] = f2b(f.w);
    ((us4v*)xb)[i] = o;
  } else if (bid < 5120) {
    const int id = bid - 4096;
    const int z = id >> 8, rem = id & 255;
    const int bx = rem & 15, by = rem >> 4;
    const float* W = (z == 0) ? Wq : (z == 1) ? Wk : (z == 2) ? Wv : Wfc;
    const int tx = t & 31, ty = t >> 5;
    const int n0 = bx * 32, k0 = by * 32;
    #pragma unroll
    for (int r = ty; r < 32; r += 8)
      tile[r][tx] = f2b(W[(size_t)(k0 + r) * 512 + n0 + tx]);
    __syncthreads();
    unsigned short* dst = Wt + (size_t)z * 512 * 512;
    #pragma unroll
    for (int r = ty; r < 32; r += 8)
      dst[(size_t)(n0 + r) * 512 + k0 + tx] = tile[tx][r];
  } else {
    float4 zz = {0.f, 0.f, 0.f, 0.f};
    #pragma unroll
    for (int p = 0; p < 4; ++p) ((float4*)Vsum)[p * 256 + t] = zz;
  }
}

// ---------------- QKV GEMM: 256x128 tile, BK=64, fused V col sums ----------
// C[8192,1536] = A[8192,512] * Bt[1536,512]^T, bf16 out.
__global__ __launch_bounds__(512) void gemm_qkv_kernel(
    const unsigned short* __restrict__ A, const unsigned short* __restrict__ Bt,
    unsigned short* __restrict__ C, float* __restrict__ Vsum) {
  const int N = 1536, K = 512;
  __shared__ __align__(16) unsigned short smem[24576];  // 48 KB
  unsigned short* As = smem;           // 256x64 = 16384 ush
  unsigned short* Bs = smem + 16384;   // 128x64 =  8192 ush
  const int t = threadIdx.x, wave = t >> 6, lane = t & 63;
  const int wr = wave >> 1, wc = wave & 1;           // 4 x 2 wave grid
  const int quad = lane >> 4, l16 = lane & 15;
  const int bm = blockIdx.y * 256, bn = blockIdx.x * 128;

  const unsigned short *gA[4], *gB[2];
  #pragma unroll
  for (int p = 0; p < 4; ++p) {
    const int ci = wave * 256 + p * 64 + lane;       // A: 2048 chunks
    const int r = ci >> 3, c = (ci & 7) ^ (r & 7);
    gA[p] = A + (size_t)(bm + r) * K + c * 8;
  }
  #pragma unroll
  for (int p = 0; p < 2; ++p) {
    const int ci = wave * 128 + p * 64 + lane;       // B: 1024 chunks
    const int r = ci >> 3, c = (ci & 7) ^ (r & 7);
    gB[p] = Bt + (size_t)(bn + r) * K + c * 8;
  }

  f4v acc[4][4];
  #pragma unroll
  for (int i = 0; i < 4; ++i)
    #pragma unroll
    for (int j = 0; j < 4; ++j) {
      f4v z = {0.f, 0.f, 0.f, 0.f};
      acc[i][j] = z;
    }

  for (int kt = 0; kt < K; kt += 64) {
    #pragma unroll
    for (int p = 0; p < 4; ++p)
      gload_lds16(gA[p] + kt, As + wave * 2048 + p * 512);
    #pragma unroll
    for (int p = 0; p < 2; ++p)
      gload_lds16(gB[p] + kt, Bs + wave * 1024 + p * 512);
    __syncthreads();

    #pragma unroll
    for (int s = 0; s < 2; ++s) {
      s8v af[4], bf[4];
      #pragma unroll
      for (int i = 0; i < 4; ++i) {
        const int r = wr * 64 + i * 16 + l16;
        af[i] = *(const s8v*)&As[(r * 8 + ((quad + 4 * s) ^ (r & 7))) * 8];
      }
      #pragma unroll
      for (int j = 0; j < 4; ++j) {
        const int r = wc * 64 + j * 16 + l16;
        bf[j] = *(const s8v*)&Bs[(r * 8 + ((quad + 4 * s) ^ (r & 7))) * 8];
      }
      #pragma unroll
      for (int i = 0; i < 4; ++i)
        #pragma unroll
        for (int j = 0; j < 4; ++j)
          acc[i][j] = __builtin_amdgcn_mfma_f32_16x16x32_bf16(
              af[i], bf[j], acc[i][j], 0, 0, 0);
    }
    __syncthreads();
  }

  // fused V column sums (fp32, quad-reduce + one atomic per col per block)
  if (bn >= 1024) {
    const int b = blockIdx.y >> 2;
    #pragma unroll
    for (int j = 0; j < 4; ++j) {
      float ps = 0.f;
      #pragma unroll
      for (int i = 0; i < 4; ++i)
        #pragma unroll
        for (int r = 0; r < 4; ++r) ps += acc[i][j][r];
      ps += __shfl_xor(ps, 16);
      ps += __shfl_xor(ps, 32);
      if (quad == 0)
        atomicAdd(&Vsum[b * 512 + (bn - 1024) + wc * 64 + j * 16 + l16], ps);
    }
  }

  // bf16 C: two-pass LDS bounce (128 rows each) -> coalesced us8v stores
  #pragma unroll
  for (int h2 = 0; h2 < 2; ++h2) {
    if ((wr >> 1) == h2) {
      #pragma unroll
      for (int i = 0; i < 4; ++i) {
        const int lr0 = (wr & 1) * 64 + i * 16 + quad * 4;
        #pragma unroll
        for (int j = 0; j < 4; ++j) {
          const int lc = wc * 64 + j * 16 + l16;
          #pragma unroll
          for (int r = 0; r < 4; ++r)
            smem[(lr0 + r) * 128 + lc] = f2b(acc[i][j][r]);
        }
      }
    }
    __syncthreads();
    #pragma unroll
    for (int p = 0; p < 4; ++p) {
      const int row = p * 32 + (t >> 4);
      const int ch  = t & 15;
      *(us8v*)(C + (size_t)(bm + h2 * 128 + row) * N + bn + ch * 8) =
          *(const us8v*)&smem[row * 128 + ch * 8];
    }
    __syncthreads();
  }
}

// ---------------- fused band-attention + FC GEMM + residual + LN -----------
// Grid 256: block = (b, 32-q-row chunk). 512 threads (8 waves).
// Phase A: stage Q(32) K(34) V(34) rows x 512 cols (stride 520 ush);
//   closed-form band softmax; ctx -> LDS in FC A-swizzle layout.
// Phase B: BK=32 dbuf FC GEMM (Wfc^T streamed via global_load_lds);
//   epilogue residual(bf16 xb) + LayerNorm -> y.
#define KS 520          // phase-A row stride (ush)
#define CTXO 0          // ctxS: 16384 ush
#define VSO  16384      // vs:   1024 ush (512 f32)
#define WKO  17408      // work area
__global__ __launch_bounds__(512) void attn_fcln_kernel(
    const unsigned short* __restrict__ QKV, const float* __restrict__ Vsum,
    const unsigned short* __restrict__ Bt,   // Wfc^T bf16 [512][512]
    const unsigned short* __restrict__ xb, const float* __restrict__ gamma,
    const float* __restrict__ beta, float* __restrict__ y) {
  __shared__ __align__(16) unsigned short smem[69408];  // ~135.6 KB
  unsigned short* ctxS = smem + CTXO;
  float* vs = (float*)(smem + VSO);
  unsigned short* WK = smem + WKO;
  unsigned short* Qs = WK;               // 32*520 = 16640
  unsigned short* Ks = WK + 16640;       // 34*520 = 17680
  unsigned short* Vs = WK + 34320;       // 34*520 = 17680

  const int t = threadIdx.x, wave = t >> 6, lane = t & 63;
  const int quad = lane >> 4, l16 = lane & 15;
  const int b = blockIdx.x >> 5, chunk = blockIdx.x & 31;
  const int q0 = chunk * 32;
  const size_t rowb = ((size_t)b * 1024) * 1536;

  // ---- phase A: stage Q/K/V (halo-clamped) ----
  for (int i = t; i < 6400; i += 512) {
    int row, ch, off;
    unsigned short* dst;
    if (i < 2048) { row = i >> 6; ch = i & 63; off = 0;
                    dst = Qs + row * KS + ch * 8; row = q0 + row; }
    else if (i < 4224) { int k = i - 2048; row = k >> 6; ch = k & 63; off = 512;
                    dst = Ks + (k >> 6) * KS + ch * 8;
                    row = q0 - 1 + row; row = row < 0 ? 0 : (row > 1023 ? 1023 : row); }
    else { int k = i - 4224; row = k >> 6; ch = k & 63; off = 1024;
                    dst = Vs + (k >> 6) * KS + ch * 8;
                    row = q0 - 1 + row; row = row < 0 ? 0 : (row > 1023 ? 1023 : row); }
    *(us8v*)dst = *(const us8v*)(QKV + rowb + (size_t)row * 1536 + off + ch * 8);
  }
  vs[t] = Vsum[b * 512 + t];
  __syncthreads();

  // ---- band softmax (2 threads per (q,h): halves of 64 dims) ----
  {
    const int pair = t >> 1, half = t & 1;
    const int qr = pair & 31, h = pair >> 5;
    const int q = q0 + qr;
    const int colb = h * 64 + half * 32;
    float pm = 0.f, p0 = 0.f, pp = 0.f;
    #pragma unroll
    for (int jj = 0; jj < 4; ++jj) {
      const us8v qv = *(const us8v*)&Qs[qr * KS + colb + jj * 8];
      const us8v km = *(const us8v*)&Ks[qr * KS + colb + jj * 8];
      const us8v k0 = *(const us8v*)&Ks[(qr + 1) * KS + colb + jj * 8];
      const us8v kp = *(const us8v*)&Ks[(qr + 2) * KS + colb + jj * 8];
      #pragma unroll
      for (int r = 0; r < 8; ++r) {
        const float qf = b2f(qv[r]);
        pm += qf * b2f(km[r]);
        p0 += qf * b2f(k0[r]);
        pp += qf * b2f(kp[r]);
      }
    }
    pm += __shfl_xor(pm, 1);
    p0 += __shfl_xor(p0, 1);
    pp += __shfl_xor(pp, 1);

    const float OFF = -1e-9f;
    const float s0 = p0 * 0.125f;
    const float sm = (q > 0)    ? pm * 0.125f : OFF;
    const float sp = (q < 1023) ? pp * 0.125f : OFF;
    const float m  = fmaxf(fmaxf(s0, sm), fmaxf(sp, OFF));
    const float e0 = __expf(s0 - m), em = __expf(sm - m), ep = __expf(sp - m);
    const float eoff = __expf(OFF - m);
    const float inv  = 1.f / (e0 + em + ep + 1021.f * eoff);
    const float wm = (em - eoff) * inv, w0 = (e0 - eoff) * inv,
                wp = (ep - eoff) * inv, wt = eoff * inv;

    #pragma unroll
    for (int jj = 0; jj < 4; ++jj) {
      const us8v a  = *(const us8v*)&Vs[qr * KS + colb + jj * 8];
      const us8v v0 = *(const us8v*)&Vs[(qr + 1) * KS + colb + jj * 8];
      const us8v c  = *(const us8v*)&Vs[(qr + 2) * KS + colb + jj * 8];
      const float4 va = *(const float4*)&vs[colb + jj * 8];
      const float4 vb = *(const float4*)&vs[colb + jj * 8 + 4];
      us8v o;
      #pragma unroll
      for (int r = 0; r < 4; ++r) {
        const float base = (r == 0) ? va.x : (r == 1) ? va.y : (r == 2) ? va.z : va.w;
        o[r] = f2b(wt * base + wm * b2f(a[r]) + w0 * b2f(v0[r]) + wp * b2f(c[r]));
      }
      #pragma unroll
      for (int r = 4; r < 8; ++r) {
        const float base = (r == 4) ? vb.x : (r == 5) ? vb.y : (r == 6) ? vb.z : vb.w;
        o[r] = f2b(wt * base + wm * b2f(a[r]) + w0 * b2f(v0[r]) + wp * b2f(c[r]));
      }
      // ctx in FC A-swizzle layout: chunk c = h*8 + half*4 + jj
      const int slot = h * 8 + ((half * 4 + jj) ^ (qr & 7));
      *(us8v*)&ctxS[qr * 512 + slot * 8] = o;
    }
  }
  __syncthreads();

  // ---- phase B: FC GEMM (BK=32, dbuf) ----
  const int wrr = wave >> 2, wcc = wave & 3;   // 2 x 4 wave grid
  const unsigned short* gB[4];
  #pragma unroll
  for (int p = 0; p < 4; ++p) {
    const int ci = wave * 256 + p * 64 + lane;  // 2048 chunks (512 rows x 4)
    const int R = ci >> 3, pos = (ci & 7) ^ (R & 7);
    gB[p] = Bt + (size_t)(2 * R + (pos >> 2)) * 512 + (pos & 3) * 8;
  }

  f4v acc[8];
  #pragma unroll
  for (int j = 0; j < 8; ++j) {
    f4v z = {0.f, 0.f, 0.f, 0.f};
    acc[j] = z;
  }

  #pragma unroll
  for (int p = 0; p < 4; ++p)
    gload_lds16(gB[p], WK + wave * 2048 + p * 512);
  __syncthreads();

  for (int it = 0; it < 16; ++it) {
    const unsigned short* Bb = WK + (it & 1) * 16384;
    const int rm = wrr * 16 + l16;
    const int c = it * 4 + quad;
    const int slot = (c & ~7) | ((c & 7) ^ (rm & 7));
    const s8v af = *(const s8v*)&ctxS[rm * 512 + slot * 8];
    s8v bf[8];
    #pragma unroll
    for (int j = 0; j < 8; ++j) {
      const int n = wcc * 128 + j * 16 + l16;
      bf[j] = *(const s8v*)&Bb[(n >> 1) * 64 +
                               ((((n & 1) * 4 + quad) ^ ((n >> 1) & 7)) * 8)];
    }
    if (it < 15) {
      const int kt = (it + 1) * 32;
      unsigned short* nb = WK + ((it & 1) ^ 1) * 16384 + wave * 2048;
      #pragma unroll
      for (int p = 0; p < 4; ++p)
        gload_lds16(gB[p] + kt, nb + p * 512);
    }
    #pragma unroll
    for (int j = 0; j < 8; ++j)
      acc[j] = __builtin_amdgcn_mfma_f32_16x16x32_bf16(af, bf[j], acc[j], 0, 0, 0);
    __syncthreads();
  }

  // ---- epilogue: acc -> LDS fp32, residual + LN ----
  float* outS = (float*)WK;
  #pragma unroll
  for (int j = 0; j < 8; ++j) {
    const int col = wcc * 128 + j * 16 + l16;
    const int row0 = wrr * 16 + quad * 4;
    #pragma unroll
    for (int r = 0; r < 4; ++r)
      outS[(row0 + r) * 516 + col] = acc[j][r];
  }
  __syncthreads();

  const int row = t >> 4, l = t & 15;
  const size_t gbase = ((size_t)(b * 1024 + q0 + row)) * 512;
  float4 v[8];
  float s1 = 0.f, s2 = 0.f;
  #pragma unroll
  for (int k = 0; k < 8; ++k) {
    const int c = k * 64 + l * 4;
    const float4 a = *(const float4*)&outS[row * 516 + c];
    const us4v xv = *(const us4v*)&xb[gbase + c];
    float4 w;
    w.x = a.x + b2f(xv[0]); w.y = a.y + b2f(xv[1]);
    w.z = a.z + b2f(xv[2]); w.w = a.w + b2f(xv[3]);
    v[k] = w;
    s1 += w.x + w.y + w.z + w.w;
    s2 += w.x * w.x + w.y * w.y + w.z * w.z + w.w * w.w;
  }
  #pragma unroll
  for (int m = 1; m < 16; m <<= 1) {
    s1 += __shfl_xor(s1, m);
    s2 += __shfl_xor(s2, m);
  }
  const float mu  = s1 * (1.f / 512.f);
  const float var = s2 * (1.f / 512.f) - mu * mu;
  const float rs  = rsqrtf(var + 1e-5f);
  #pragma unroll
  for (int k = 0; k < 8; ++k) {
    const int c = k * 64 + l * 4;
    const float4 g  = *(const float4*)&gamma[c];
    const float4 bb = *(const float4*)&beta[c];
    float4 o;
    o.x = (v[k].x - mu) * rs * g.x + bb.x;
    o.y = (v[k].y - mu) * rs * g.y + bb.y;
    o.z = (v[k].z - mu) * rs * g.z + bb.z;
    o.w = (v[k].w - mu) * rs * g.w + bb.w;
    *(float4*)&y[gbase + c] = o;
  }
}

// ---------------------------------------------------------------------------
extern "C" void kernel_launch(void* const* d_in, const int* in_sizes, int n_in,
                              void* d_out, int out_size, void* d_ws, size_t ws_size,
                              hipStream_t stream) {
  const float* x     = (const float*)d_in[0];
  const float* Wq    = (const float*)d_in[1];
  const float* Wk    = (const float*)d_in[2];
  const float* Wv    = (const float*)d_in[3];
  const float* Wfc   = (const float*)d_in[4];
  const float* gamma = (const float*)d_in[5];
  const float* beta  = (const float*)d_in[6];
  float* y = (float*)d_out;

  char* ws = (char*)d_ws;
  unsigned short* Wt   = (unsigned short*)(ws);              // 2 MiB
  unsigned short* xb   = (unsigned short*)(ws + 2097152);    // 8 MiB
  unsigned short* QKV  = (unsigned short*)(ws + 10485760);   // 24 MiB
  float*          Vsum = (float*)(ws + 35651584);            // 16 KiB

  conv_kernel<<<5121, 256, 0, stream>>>(x, Wq, Wk, Wv, Wfc, xb, Wt, Vsum);
  gemm_qkv_kernel<<<dim3(12, 32), 512, 0, stream>>>(xb, Wt, QKV, Vsum);
  attn_fcln_kernel<<<256, 512, 0, stream>>>(
      QKV, Vsum, Wt + (size_t)1536 * 512, xb, gamma, beta, y);
}

// Round 8
// 122.141 us; speedup vs baseline: 1.1122x; 1.1122x over previous
//
#include <hip/hip_runtime.h>
#include <math.h>

// ---------------------------------------------------------------------------
// MultiAttention, 4 launches (round-6 structure, measured best):
//  1) conv: x->bf16, W->bf16^T, Vsum=0
//  2) gemm_qkv: 128x128 tile, 256 thr (768 blocks = 3/CU exact), BK=64,
//     global_load_lds + XOR-swizzled source, fused V col sums (atomics)
//  3) attn: per (b,h,128-q chunk), Q/K/V LDS-staged, closed-form band softmax
//  4) gemm_fcln: 32x512 tile, BK=64 LDS double-buffer, one barrier/iter,
//     DMA under the MFMA chain; epilogue residual(bf16) + LayerNorm.
// NOTE (R7 lesson): grids must be integral blocks/CU (>=2) — 1.5 blocks/CU
// tails and 1-block/CU mega-fusions both regressed.
// ---------------------------------------------------------------------------

typedef short     s8v  __attribute__((ext_vector_type(8)));   // 8 bf16
typedef float     f4v  __attribute__((ext_vector_type(4)));
typedef unsigned short us4v __attribute__((ext_vector_type(4)));
typedef unsigned short us8v __attribute__((ext_vector_type(8)));

__device__ __forceinline__ unsigned short f2b(float f) {
  union { float f; unsigned int u; } v; v.f = f;
  unsigned int u = v.u;
  return (unsigned short)((u + 0x7fffu + ((u >> 16) & 1u)) >> 16);  // RNE
}
__device__ __forceinline__ float b2f(unsigned short u) {
  union { unsigned int i; float f; } v; v.i = ((unsigned int)u) << 16;
  return v.f;
}
__device__ __forceinline__ void gload_lds16(const void* g, void* l) {
  __builtin_amdgcn_global_load_lds(
      (const __attribute__((address_space(1))) void*)g,
      (__attribute__((address_space(3))) void*)l, 16, 0, 0);
}

// ---------------- conv: x->bf16, W->bf16 transposed, Vsum=0 ----------------
__global__ __launch_bounds__(256) void conv_kernel(
    const float* __restrict__ x,
    const float* __restrict__ Wq, const float* __restrict__ Wk,
    const float* __restrict__ Wv, const float* __restrict__ Wfc,
    unsigned short* __restrict__ xb, unsigned short* __restrict__ Wt,
    float* __restrict__ Vsum) {
  __shared__ unsigned short tile[32][33];
  const int bid = blockIdx.x, t = threadIdx.x;
  if (bid < 4096) {
    const int i = bid * 256 + t;
    const float4 f = ((const float4*)x)[i];
    us4v o; o[0] = f2b(f.x); o[1] = f2b(f.y); o[2] = f2b(f.z); o[3] = f2b(f.w);
    ((us4v*)xb)[i] = o;
  } else if (bid < 5120) {
    const int id = bid - 4096;
    const int z = id >> 8, rem = id & 255;
    const int bx = rem & 15, by = rem >> 4;
    const float* W = (z == 0) ? Wq : (z == 1) ? Wk : (z == 2) ? Wv : Wfc;
    const int tx = t & 31, ty = t >> 5;
    const int n0 = bx * 32, k0 = by * 32;
    #pragma unroll
    for (int r = ty; r < 32; r += 8)
      tile[r][tx] = f2b(W[(size_t)(k0 + r) * 512 + n0 + tx]);
    __syncthreads();
    unsigned short* dst = Wt + (size_t)z * 512 * 512;
    #pragma unroll
    for (int r = ty; r < 32; r += 8)
      dst[(size_t)(n0 + r) * 512 + k0 + tx] = tile[tx][r];
  } else {
    float4 zz = {0.f, 0.f, 0.f, 0.f};
    #pragma unroll
    for (int p = 0; p < 4; ++p) ((float4*)Vsum)[p * 256 + t] = zz;
  }
}

// ---------------- QKV GEMM (bf16 out, BK=64) + fused V column sums ---------
// C[8192,1536] = A[8192,512] * Bt[1536,512]^T.
// LDS slot (row r, chunk cs) holds global k-chunk cs^(r&7) => fragment
// ds_read_b128 lands 2-way/bank (free).
__global__ __launch_bounds__(256) void gemm_qkv_kernel(
    const unsigned short* __restrict__ A, const unsigned short* __restrict__ Bt,
    unsigned short* __restrict__ C, float* __restrict__ Vsum) {
  const int N = 1536, K = 512;
  __shared__ __align__(16) unsigned short smem[16384];  // 32 KB
  unsigned short* As = smem;          // 128x64 = 8192 ush
  unsigned short* Bs = smem + 8192;
  const int t = threadIdx.x, wave = t >> 6, lane = t & 63;
  const int wr = wave >> 1, wc = wave & 1;
  const int quad = lane >> 4, l16 = lane & 15;
  const int bm = blockIdx.y * 128, bn = blockIdx.x * 128;

  const unsigned short *gA[4], *gB[4];
  #pragma unroll
  for (int p = 0; p < 4; ++p) {
    const int ci = wave * 256 + p * 64 + lane;
    const int r = ci >> 3, c = (ci & 7) ^ (r & 7);
    gA[p] = A + (size_t)(bm + r) * K + c * 8;
    gB[p] = Bt + (size_t)(bn + r) * K + c * 8;
  }

  f4v acc[4][4];
  #pragma unroll
  for (int i = 0; i < 4; ++i)
    #pragma unroll
    for (int j = 0; j < 4; ++j) {
      f4v z = {0.f, 0.f, 0.f, 0.f};
      acc[i][j] = z;
    }

  #pragma unroll
  for (int it = 0; it < 8; ++it) {
    const int kt = it * 64;
    #pragma unroll
    for (int p = 0; p < 4; ++p)
      gload_lds16(gA[p] + kt, As + wave * 2048 + p * 512);
    #pragma unroll
    for (int p = 0; p < 4; ++p)
      gload_lds16(gB[p] + kt, Bs + wave * 2048 + p * 512);
    __syncthreads();

    #pragma unroll
    for (int s = 0; s < 2; ++s) {
      s8v af[4], bf[4];
      #pragma unroll
      for (int i = 0; i < 4; ++i) {
        const int r = wr * 64 + i * 16 + l16;
        af[i] = *(const s8v*)&As[(r * 8 + ((quad + 4 * s) ^ (r & 7))) * 8];
      }
      #pragma unroll
      for (int j = 0; j < 4; ++j) {
        const int r = wc * 64 + j * 16 + l16;
        bf[j] = *(const s8v*)&Bs[(r * 8 + ((quad + 4 * s) ^ (r & 7))) * 8];
      }
      #pragma unroll
      for (int i = 0; i < 4; ++i)
        #pragma unroll
        for (int j = 0; j < 4; ++j)
          acc[i][j] = __builtin_amdgcn_mfma_f32_16x16x32_bf16(
              af[i], bf[j], acc[i][j], 0, 0, 0);
    }
    __syncthreads();
  }

  // fused V column sums (fp32 acc, quad-reduced, atomic per column)
  if (bn >= 1024) {
    const int b = bm >> 10;
    #pragma unroll
    for (int j = 0; j < 4; ++j) {
      float ps = 0.f;
      #pragma unroll
      for (int i = 0; i < 4; ++i)
        #pragma unroll
        for (int r = 0; r < 4; ++r) ps += acc[i][j][r];
      ps += __shfl_xor(ps, 16);
      ps += __shfl_xor(ps, 32);
      if (quad == 0)
        atomicAdd(&Vsum[b * 512 + (bn - 1024) + wc * 64 + j * 16 + l16], ps);
    }
  }

  // bf16 C via LDS bounce -> coalesced 16B stores
  #pragma unroll
  for (int i = 0; i < 4; ++i) {
    const int lr0 = wr * 64 + i * 16 + quad * 4;
    #pragma unroll
    for (int j = 0; j < 4; ++j) {
      const int lc = wc * 64 + j * 16 + l16;
      #pragma unroll
      for (int r = 0; r < 4; ++r)
        smem[(lr0 + r) * 128 + lc] = f2b(acc[i][j][r]);
    }
  }
  __syncthreads();
  #pragma unroll
  for (int p = 0; p < 8; ++p) {
    const int row = p * 16 + (t >> 4);
    const int ch  = t & 15;
    *(us8v*)(C + (size_t)(bm + row) * N + bn + ch * 8) =
        *(const us8v*)&smem[row * 128 + ch * 8];
  }
}

// ---------------- band attention (closed-form softmax tail) ----------------
// Q, K, V all LDS-staged (coalesced 128B row slices). 512 blocks = 2/CU.
#define KVS 68
__global__ __launch_bounds__(256) void attn_kernel(
    const unsigned short* __restrict__ QKV, const float* __restrict__ Vsum,
    unsigned short* __restrict__ ctx) {
  __shared__ __align__(16) unsigned short Qs[130 * KVS];
  __shared__ __align__(16) unsigned short Ks[130 * KVS];
  __shared__ __align__(16) unsigned short Vs[130 * KVS];
  __shared__ __align__(16) float vs_s[64];
  const int bh = blockIdx.x;
  const int b = bh >> 3, h = bh & 7;
  const int q0 = blockIdx.y * 128;
  const int t = threadIdx.x;
  const size_t rowb = ((size_t)b * 1024) * 1536;

  #pragma unroll
  for (int p = 0; p < 5; ++p) {
    const int i = p * 32 + (t >> 3);
    if (i < 130) {
      int g = q0 - 1 + i;
      g = g < 0 ? 0 : (g > 1023 ? 1023 : g);
      const unsigned short* src =
          QKV + rowb + (size_t)g * 1536 + h * 64 + (t & 7) * 8;
      const us8v qv = *(const us8v*)(src);
      const us8v kv = *(const us8v*)(src + 512);
      const us8v vv = *(const us8v*)(src + 1024);
      us4v lo, hi;
      #pragma unroll
      for (int r = 0; r < 4; ++r) { lo[r] = qv[r]; hi[r] = qv[r + 4]; }
      *(us4v*)&Qs[i * KVS + (t & 7) * 8]     = lo;
      *(us4v*)&Qs[i * KVS + (t & 7) * 8 + 4] = hi;
      #pragma unroll
      for (int r = 0; r < 4; ++r) { lo[r] = kv[r]; hi[r] = kv[r + 4]; }
      *(us4v*)&Ks[i * KVS + (t & 7) * 8]     = lo;
      *(us4v*)&Ks[i * KVS + (t & 7) * 8 + 4] = hi;
      #pragma unroll
      for (int r = 0; r < 4; ++r) { lo[r] = vv[r]; hi[r] = vv[r + 4]; }
      *(us4v*)&Vs[i * KVS + (t & 7) * 8]     = lo;
      *(us4v*)&Vs[i * KVS + (t & 7) * 8 + 4] = hi;
    }
  }
  if (t < 64) vs_s[t] = Vsum[(b << 9) + h * 64 + t];
  __syncthreads();

  const int q    = q0 + (t >> 1);
  const int half = t & 1;
  const int li   = (t >> 1) + 1;
  const int co   = half * 32;

  float pm = 0.f, p0 = 0.f, pp = 0.f;
  #pragma unroll
  for (int jj = 0; jj < 8; ++jj) {
    const us4v qv = *(const us4v*)&Qs[li * KVS + co + jj * 4];
    const us4v km = *(const us4v*)&Ks[(li - 1) * KVS + co + jj * 4];
    const us4v k0 = *(const us4v*)&Ks[li * KVS + co + jj * 4];
    const us4v kp = *(const us4v*)&Ks[(li + 1) * KVS + co + jj * 4];
    #pragma unroll
    for (int r = 0; r < 4; ++r) {
      const float qf = b2f(qv[r]);
      pm += qf * b2f(km[r]);
      p0 += qf * b2f(k0[r]);
      pp += qf * b2f(kp[r]);
    }
  }
  pm += __shfl_xor(pm, 1);
  p0 += __shfl_xor(p0, 1);
  pp += __shfl_xor(pp, 1);

  const float OFF = -1e-9f;
  const float s0 = p0 * 0.125f;
  const float sm = (q > 0)    ? pm * 0.125f : OFF;
  const float sp = (q < 1023) ? pp * 0.125f : OFF;
  const float m  = fmaxf(fmaxf(s0, sm), fmaxf(sp, OFF));
  const float e0 = __expf(s0 - m), em = __expf(sm - m), ep = __expf(sp - m);
  const float eoff = __expf(OFF - m);
  const float inv  = 1.f / (e0 + em + ep + 1021.f * eoff);
  const float wm = (em - eoff) * inv, w0 = (e0 - eoff) * inv,
              wp = (ep - eoff) * inv, wt = eoff * inv;

  unsigned short* cp = ctx + ((size_t)(b * 1024 + q)) * 512 + h * 64 + co;
  #pragma unroll
  for (int jj = 0; jj < 8; ++jj) {
    const us4v a  = *(const us4v*)&Vs[(li - 1) * KVS + co + jj * 4];
    const us4v v0 = *(const us4v*)&Vs[li * KVS + co + jj * 4];
    const us4v c  = *(const us4v*)&Vs[(li + 1) * KVS + co + jj * 4];
    const float4 vsv = *(const float4*)&vs_s[co + jj * 4];
    us4v o;
    o[0] = f2b(wt * vsv.x + wm * b2f(a[0]) + w0 * b2f(v0[0]) + wp * b2f(c[0]));
    o[1] = f2b(wt * vsv.y + wm * b2f(a[1]) + w0 * b2f(v0[1]) + wp * b2f(c[1]));
    o[2] = f2b(wt * vsv.z + wm * b2f(a[2]) + w0 * b2f(v0[2]) + wp * b2f(c[2]));
    o[3] = f2b(wt * vsv.w + wm * b2f(a[3]) + w0 * b2f(v0[3]) + wp * b2f(c[3]));
    *(us4v*)(cp + jj * 4) = o;
  }
}

// ---------------- FC GEMM fused with residual + LayerNorm ------------------
// Block: 32 rows x 512 cols; 512 threads = 8 waves (2 row-groups x 4 col).
// BK=64, LDS double-buffered (68 KB x2), ONE barrier per iter; next-tile DMA
// issued under the MFMA chain (1 block/CU => explicit overlap required).
#define OS 516  // f32 row stride in LDS epilogue

__global__ __launch_bounds__(512) void gemm_fcln_kernel(
    const unsigned short* __restrict__ A,   // ctx [8192,512] bf16
    const unsigned short* __restrict__ Bt,  // Wfc^T [512,512] bf16
    const unsigned short* __restrict__ xb, const float* __restrict__ gamma,
    const float* __restrict__ beta, float* __restrict__ y) {
  const int K = 512;
  // buffer: A 32x64 = 2048 ush, B 512x64 = 32768 ush -> 34816 ush; x2 = 136 KB
  __shared__ __align__(16) unsigned short smem[69632];
  float* outS = (float*)smem;

  const int t = threadIdx.x, wave = t >> 6, lane = t & 63;
  const int wrr = wave >> 2, wcc = wave & 3;
  const int quad = lane >> 4, l16 = lane & 15;
  const int bm = blockIdx.x * 32;

  // A staging: 256 chunks, waves 0..3 one instr each
  const int ciA = wave * 64 + lane;
  const int rA = ciA >> 3, cA = (ciA & 7) ^ (rA & 7);
  const unsigned short* gA = A + (size_t)(bm + rA) * K + cA * 8;
  // B staging: 4096 chunks, 8 instrs per wave
  const unsigned short* gB[8];
  #pragma unroll
  for (int p = 0; p < 8; ++p) {
    const int ci = wave * 512 + p * 64 + lane;
    const int r = ci >> 3, c = (ci & 7) ^ (r & 7);
    gB[p] = Bt + (size_t)r * K + c * 8;
  }

  f4v acc[8];
  #pragma unroll
  for (int j = 0; j < 8; ++j) {
    f4v z = {0.f, 0.f, 0.f, 0.f};
    acc[j] = z;
  }

  // prologue: stage k-tile 0 into buffer 0
  if (wave < 4) gload_lds16(gA, smem + wave * 512);
  #pragma unroll
  for (int p = 0; p < 8; ++p)
    gload_lds16(gB[p], smem + 2048 + wave * 4096 + p * 512);
  __syncthreads();

  #pragma unroll
  for (int it = 0; it < 8; ++it) {
    const int cur = (it & 1) * 34816;
    const int nxt = 34816 - cur;
    const unsigned short* Ab = smem + cur;
    const unsigned short* Bb = smem + cur + 2048;
    const int rm = wrr * 16 + l16;
    const s8v af0 = *(const s8v*)&Ab[(rm * 8 + (quad ^ (rm & 7))) * 8];
    const s8v af1 = *(const s8v*)&Ab[(rm * 8 + ((quad + 4) ^ (rm & 7))) * 8];
    s8v bf0[8];
    #pragma unroll
    for (int j = 0; j < 8; ++j) {
      const int n = wcc * 128 + j * 16 + l16;
      bf0[j] = *(const s8v*)&Bb[(n * 8 + (quad ^ (n & 7))) * 8];
    }
    if (it < 7) {  // DMA next tile; runs under the MFMA chain
      const int kt = (it + 1) * 64;
      if (wave < 4) gload_lds16(gA + kt, smem + nxt + wave * 512);
      #pragma unroll
      for (int p = 0; p < 8; ++p)
        gload_lds16(gB[p] + kt, smem + nxt + 2048 + wave * 4096 + p * 512);
    }
    #pragma unroll
    for (int j = 0; j < 8; ++j)
      acc[j] = __builtin_amdgcn_mfma_f32_16x16x32_bf16(af0, bf0[j], acc[j], 0, 0, 0);
    #pragma unroll
    for (int j = 0; j < 8; ++j) {
      const int n = wcc * 128 + j * 16 + l16;
      const s8v bf1 = *(const s8v*)&Bb[(n * 8 + ((quad + 4) ^ (n & 7))) * 8];
      acc[j] = __builtin_amdgcn_mfma_f32_16x16x32_bf16(af1, bf1, acc[j], 0, 0, 0);
    }
    __syncthreads();  // drains reads of cur + DMA into nxt
  }

  // acc -> LDS fp32
  #pragma unroll
  for (int j = 0; j < 8; ++j) {
    const int col = wcc * 128 + j * 16 + l16;
    const int row0 = wrr * 16 + quad * 4;
    #pragma unroll
    for (int r = 0; r < 4; ++r)
      outS[(row0 + r) * OS + col] = acc[j][r];
  }
  __syncthreads();

  // residual (bf16 xb) + LN: 16 threads per row
  const int row = t >> 4, l = t & 15;
  const size_t gbase = (size_t)(bm + row) * 512;
  float4 v[8];
  float s1 = 0.f, s2 = 0.f;
  #pragma unroll
  for (int k = 0; k < 8; ++k) {
    const int c = k * 64 + l * 4;
    const float4 a = *(const float4*)&outS[row * OS + c];
    const us4v xv = *(const us4v*)&xb[gbase + c];
    float4 w;
    w.x = a.x + b2f(xv[0]); w.y = a.y + b2f(xv[1]);
    w.z = a.z + b2f(xv[2]); w.w = a.w + b2f(xv[3]);
    v[k] = w;
    s1 += w.x + w.y + w.z + w.w;
    s2 += w.x * w.x + w.y * w.y + w.z * w.z + w.w * w.w;
  }
  #pragma unroll
  for (int m = 1; m < 16; m <<= 1) {
    s1 += __shfl_xor(s1, m);
    s2 += __shfl_xor(s2, m);
  }
  const float mu  = s1 * (1.f / 512.f);
  const float var = s2 * (1.f / 512.f) - mu * mu;
  const float rs  = rsqrtf(var + 1e-5f);
  #pragma unroll
  for (int k = 0; k < 8; ++k) {
    const int c = k * 64 + l * 4;
    const float4 g  = *(const float4*)&gamma[c];
    const float4 bb = *(const float4*)&beta[c];
    float4 o;
    o.x = (v[k].x - mu) * rs * g.x + bb.x;
    o.y = (v[k].y - mu) * rs * g.y + bb.y;
    o.z = (v[k].z - mu) * rs * g.z + bb.z;
    o.w = (v[k].w - mu) * rs * g.w + bb.w;
    *(float4*)&y[gbase + c] = o;
  }
}

// ---------------------------------------------------------------------------
extern "C" void kernel_launch(void* const* d_in, const int* in_sizes, int n_in,
                              void* d_out, int out_size, void* d_ws, size_t ws_size,
                              hipStream_t stream) {
  const float* x     = (const float*)d_in[0];
  const float* Wq    = (const float*)d_in[1];
  const float* Wk    = (const float*)d_in[2];
  const float* Wv    = (const float*)d_in[3];
  const float* Wfc   = (const float*)d_in[4];
  const float* gamma = (const float*)d_in[5];
  const float* beta  = (const float*)d_in[6];
  float* y = (float*)d_out;

  char* ws = (char*)d_ws;
  unsigned short* Wt   = (unsigned short*)(ws);              // 2 MiB
  unsigned short* xb   = (unsigned short*)(ws + 2097152);    // 8 MiB
  unsigned short* QKV  = (unsigned short*)(ws + 10485760);   // 24 MiB
  float*          Vsum = (float*)(ws + 35651584);            // 16 KiB
  unsigned short* ctx  = (unsigned short*)(ws + 35667968);   // 8 MiB

  conv_kernel<<<5121, 256, 0, stream>>>(x, Wq, Wk, Wv, Wfc, xb, Wt, Vsum);
  gemm_qkv_kernel<<<dim3(12, 64), 256, 0, stream>>>(xb, Wt, QKV, Vsum);
  attn_kernel<<<dim3(64, 8), 256, 0, stream>>>(QKV, Vsum, ctx);
  gemm_fcln_kernel<<<256, 512, 0, stream>>>(
      ctx, Wt + (size_t)1536 * 512, xb, gamma, beta, y);
}